// Round 5
// baseline (224.258 us; speedup 1.0000x reference)
//
#include <hip/hip_runtime.h>
#include <hip/hip_bf16.h>

#define N_ROWS 16384
#define D_COLS 2048
#define NUM_LABELS 1024
#define NUM_CAMS 8
#define NUM_SEG (NUM_LABELS * NUM_CAMS)   // 8192
#define MAXPER 64                          // list capacity per segment
#define R_REG 12                           // rows cached in registers (P(cnt>12) ~ 3e-7 per seg)
#define F4_PER_ROW (D_COLS / 4)            // 512 float4 per row
#define NUM_BLOCKS (NUM_SEG * 2)           // one block per (segment, column-half)

// ---------------- kernel 1: build per-segment row lists ----------------
__global__ void build_lists_kernel(const int* __restrict__ labels,
                                   const int* __restrict__ cams,
                                   int* __restrict__ counts,
                                   int* __restrict__ lists) {
    int i = blockIdx.x * blockDim.x + threadIdx.x;
    if (i < N_ROWS) {
        int seg = labels[i] * NUM_CAMS + cams[i];
        int pos = atomicAdd(&counts[seg], 1);
        if (pos < MAXPER) lists[seg * MAXPER + pos] = i;
    }
}

__device__ __forceinline__ float smooth_l1(float d) {
    float ad = fabsf(d);
    return ad < 1.0f ? 0.5f * d * d : ad - 0.5f;
}

// ---------------- kernel 2: one block per (segment, column-half) ----------------
// 256 threads; thread owns ONE float4: column float4 index = half*256 + tid.
// All R_REG row loads issued with NOTHING serialized before them except the
// list load itself (counts load overlaps). Rows cached in registers; single
// global pass; invalid rows masked by weight 0 (indices wrapped into range so
// the speculative loads are safe). No atomics — partial per block.
__global__ __launch_bounds__(256) void seg_loss_kernel(const float* __restrict__ feats,
                                                       const int* __restrict__ counts,
                                                       const int* __restrict__ lists,
                                                       float* __restrict__ partials) {
    int bid  = blockIdx.x;
    int seg  = bid >> 1;
    int half = bid & 1;
    int tid  = threadIdx.x;

    __shared__ int slist[R_REG];

    // stage first R_REG list entries UNCONDITIONALLY (no dependency on counts);
    // unwritten entries are 0xAA poison -> wrap into valid range, masked later.
    if (tid < R_REG)
        slist[tid] = lists[seg * MAXPER + tid] & (N_ROWS - 1);
    int cnt = counts[seg];            // overlaps with the list load
    __syncthreads();

    int rows = cnt < MAXPER ? cnt : MAXPER;

    const float4* base = (const float4*)feats + (half * 256 + tid);

    // issue ALL row loads back-to-back (12 independent loads in flight)
    float4 v[R_REG];
#pragma unroll
    for (int r = 0; r < R_REG; ++r)
        v[r] = base[(size_t)slist[r] * F4_PER_ROW];

    // masked sum
    float mx = 0.f, my = 0.f, mz = 0.f, mw = 0.f;
#pragma unroll
    for (int r = 0; r < R_REG; ++r) {
        float w = (r < rows) ? 1.0f : 0.0f;
        mx = fmaf(w, v[r].x, mx);
        my = fmaf(w, v[r].y, my);
        mz = fmaf(w, v[r].z, mz);
        mw = fmaf(w, v[r].w, mw);
    }
    // rare overflow rows (cnt > R_REG): correct slow path, ~never taken
    for (int r = R_REG; r < rows; ++r) {
        int row = lists[seg * MAXPER + r];
        float4 a = base[(size_t)row * F4_PER_ROW];
        mx += a.x; my += a.y; mz += a.z; mw += a.w;
    }

    float inv = 1.0f / (float)(cnt > 0 ? cnt : 1);
    mx *= inv; my *= inv; mz *= inv; mw *= inv;

    // SmoothL1 vs mean, straight from registers (single global pass)
    float loss = 0.0f;
#pragma unroll
    for (int r = 0; r < R_REG; ++r) {
        float w = (r < rows) ? 1.0f : 0.0f;
        loss += w * (smooth_l1(v[r].x - mx) + smooth_l1(v[r].y - my)
                   + smooth_l1(v[r].z - mz) + smooth_l1(v[r].w - mw));
    }
    for (int r = R_REG; r < rows; ++r) {      // rare overflow path
        int row = lists[seg * MAXPER + r];
        float4 a = base[(size_t)row * F4_PER_ROW];
        loss += smooth_l1(a.x - mx) + smooth_l1(a.y - my)
              + smooth_l1(a.z - mz) + smooth_l1(a.w - mw);
    }

    // block reduction: wave64 shuffle then LDS across 4 waves
    for (int o = 32; o > 0; o >>= 1)
        loss += __shfl_down(loss, o, 64);

    __shared__ float wsum[4];
    int lane = tid & 63;
    int wid  = tid >> 6;
    if (lane == 0) wsum[wid] = loss;
    __syncthreads();
    if (tid == 0)
        partials[bid] = wsum[0] + wsum[1] + wsum[2] + wsum[3];
}

// ---------------- kernel 3: reduce partials -> scalar loss ----------------
__global__ __launch_bounds__(256) void reduce_kernel(const float* __restrict__ partials,
                                                     float* __restrict__ out) {
    int tid = threadIdx.x;
    float s = 0.0f;
    for (int i = tid; i < NUM_BLOCKS; i += 256)
        s += partials[i];

    for (int o = 32; o > 0; o >>= 1)
        s += __shfl_down(s, o, 64);

    __shared__ float wsum[4];
    int lane = tid & 63;
    int wid  = tid >> 6;
    if (lane == 0) wsum[wid] = s;
    __syncthreads();
    if (tid == 0)
        out[0] = (wsum[0] + wsum[1] + wsum[2] + wsum[3])
               * (1.0f / ((float)N_ROWS * (float)D_COLS));
}

extern "C" void kernel_launch(void* const* d_in, const int* in_sizes, int n_in,
                              void* d_out, int out_size, void* d_ws, size_t ws_size,
                              hipStream_t stream) {
    const float* feats = (const float*)d_in[0];
    const int* labels  = (const int*)d_in[1];
    const int* cams    = (const int*)d_in[2];
    float* out = (float*)d_out;

    // workspace layout: counts[NUM_SEG] | lists[NUM_SEG*MAXPER] | partials[NUM_BLOCKS]
    int* counts     = (int*)d_ws;
    int* lists      = counts + NUM_SEG;
    float* partials = (float*)(lists + NUM_SEG * MAXPER);

    hipMemsetAsync(counts, 0, NUM_SEG * sizeof(int), stream);   // only counts need zeroing

    build_lists_kernel<<<(N_ROWS + 255) / 256, 256, 0, stream>>>(labels, cams, counts, lists);
    seg_loss_kernel<<<NUM_BLOCKS, 256, 0, stream>>>(feats, counts, lists, partials);
    reduce_kernel<<<1, 256, 0, stream>>>(partials, out);
}

// Round 6
// 217.636 us; speedup vs baseline: 1.0304x; 1.0304x over previous
//
#include <hip/hip_runtime.h>
#include <hip/hip_bf16.h>

#define N_ROWS 16384
#define D_COLS 2048
#define NUM_LABELS 1024
#define NUM_CAMS 8
#define NUM_SEG (NUM_LABELS * NUM_CAMS)   // 8192
#define MAXPER 64                          // list capacity per segment
#define R_REG 12                           // rows cached in registers (cnt>12 -> slow path)
#define F4_PER_ROW (D_COLS / 4)            // 512 float4 per row
#define NUM_BLOCKS (NUM_SEG * 2)           // one block per (segment, column-half)

// ---------------- kernel 1: build per-segment row lists ----------------
__global__ void build_lists_kernel(const int* __restrict__ labels,
                                   const int* __restrict__ cams,
                                   int* __restrict__ counts,
                                   int* __restrict__ lists) {
    int i = blockIdx.x * blockDim.x + threadIdx.x;
    if (i < N_ROWS) {
        int seg = labels[i] * NUM_CAMS + cams[i];
        int pos = atomicAdd(&counts[seg], 1);
        if (pos < MAXPER) lists[seg * MAXPER + pos] = i;
    }
}

__device__ __forceinline__ float smooth_l1(float d) {
    float ad = fabsf(d);
    return ad < 1.0f ? 0.5f * d * d : ad - 0.5f;
}

// ---------------- kernel 2: one block per (segment, column-half) ----------------
// 256 threads; thread owns ONE float4: column float4 index = half*256 + tid.
// Single global pass: only min(cnt,R_REG) rows are loaded (uniform predication
// on the scalar `rows` — no speculative over-read), all loads independent and
// in flight together; rows cached in registers; loss computed from registers.
// No atomics — one partial per block.
__global__ __launch_bounds__(256) void seg_loss_kernel(const float* __restrict__ feats,
                                                       const int* __restrict__ counts,
                                                       const int* __restrict__ lists,
                                                       float* __restrict__ partials) {
    int bid  = blockIdx.x;
    int seg  = bid >> 1;
    int half = bid & 1;
    int tid  = threadIdx.x;

    __shared__ int slist[R_REG];

    // stage first min(cnt,R_REG) list entries; counts load overlaps list load
    int cnt = counts[seg];                       // scalar (block-uniform)
    if (tid < R_REG && tid < cnt)
        slist[tid] = lists[seg * MAXPER + tid];
    __syncthreads();

    int rows = cnt < R_REG ? cnt : R_REG;        // uniform

    const float4* base = (const float4*)feats + (half * 256 + tid);

    // issue the `rows` row loads back-to-back (uniform branches skip the rest);
    // v[r] zero-init so unloaded entries contribute exact zeros (no NaN risk)
    float4 v[R_REG];
#pragma unroll
    for (int r = 0; r < R_REG; ++r) {
        v[r] = make_float4(0.f, 0.f, 0.f, 0.f);
        if (r < rows)
            v[r] = base[(size_t)slist[r] * F4_PER_ROW];
    }

    // sum (zeros add nothing)
    float mx = 0.f, my = 0.f, mz = 0.f, mw = 0.f;
#pragma unroll
    for (int r = 0; r < R_REG; ++r) {
        mx += v[r].x; my += v[r].y; mz += v[r].z; mw += v[r].w;
    }
    // rare overflow rows (cnt > R_REG): correct slow path, ~never taken
    for (int r = R_REG; r < cnt && r < MAXPER; ++r) {
        float4 a = base[(size_t)lists[seg * MAXPER + r] * F4_PER_ROW];
        mx += a.x; my += a.y; mz += a.z; mw += a.w;
    }

    float inv = 1.0f / (float)(cnt > 0 ? cnt : 1);
    mx *= inv; my *= inv; mz *= inv; mw *= inv;

    // SmoothL1 vs mean, straight from registers; invalid rows masked by weight
    float loss = 0.0f;
#pragma unroll
    for (int r = 0; r < R_REG; ++r) {
        float w = (r < rows) ? 1.0f : 0.0f;
        loss += w * (smooth_l1(v[r].x - mx) + smooth_l1(v[r].y - my)
                   + smooth_l1(v[r].z - mz) + smooth_l1(v[r].w - mw));
    }
    for (int r = R_REG; r < cnt && r < MAXPER; ++r) {   // rare overflow path
        float4 a = base[(size_t)lists[seg * MAXPER + r] * F4_PER_ROW];
        loss += smooth_l1(a.x - mx) + smooth_l1(a.y - my)
              + smooth_l1(a.z - mz) + smooth_l1(a.w - mw);
    }

    // block reduction: wave64 shuffle then LDS across 4 waves
    for (int o = 32; o > 0; o >>= 1)
        loss += __shfl_down(loss, o, 64);

    __shared__ float wsum[4];
    int lane = tid & 63;
    int wid  = tid >> 6;
    if (lane == 0) wsum[wid] = loss;
    __syncthreads();
    if (tid == 0)
        partials[bid] = wsum[0] + wsum[1] + wsum[2] + wsum[3];
}

// ---------------- kernel 3: reduce partials -> scalar loss ----------------
__global__ __launch_bounds__(256) void reduce_kernel(const float* __restrict__ partials,
                                                     float* __restrict__ out) {
    int tid = threadIdx.x;
    float s = 0.0f;
    for (int i = tid; i < NUM_BLOCKS; i += 256)
        s += partials[i];

    for (int o = 32; o > 0; o >>= 1)
        s += __shfl_down(s, o, 64);

    __shared__ float wsum[4];
    int lane = tid & 63;
    int wid  = tid >> 6;
    if (lane == 0) wsum[wid] = s;
    __syncthreads();
    if (tid == 0)
        out[0] = (wsum[0] + wsum[1] + wsum[2] + wsum[3])
               * (1.0f / ((float)N_ROWS * (float)D_COLS));
}

extern "C" void kernel_launch(void* const* d_in, const int* in_sizes, int n_in,
                              void* d_out, int out_size, void* d_ws, size_t ws_size,
                              hipStream_t stream) {
    const float* feats = (const float*)d_in[0];
    const int* labels  = (const int*)d_in[1];
    const int* cams    = (const int*)d_in[2];
    float* out = (float*)d_out;

    // workspace layout: counts[NUM_SEG] | lists[NUM_SEG*MAXPER] | partials[NUM_BLOCKS]
    int* counts     = (int*)d_ws;
    int* lists      = counts + NUM_SEG;
    float* partials = (float*)(lists + NUM_SEG * MAXPER);

    hipMemsetAsync(counts, 0, NUM_SEG * sizeof(int), stream);   // only counts need zeroing

    build_lists_kernel<<<(N_ROWS + 255) / 256, 256, 0, stream>>>(labels, cams, counts, lists);
    seg_loss_kernel<<<NUM_BLOCKS, 256, 0, stream>>>(feats, counts, lists, partials);
    reduce_kernel<<<1, 256, 0, stream>>>(partials, out);
}